// Round 1
// baseline (499.085 us; speedup 1.0000x reference)
//
#include <hip/hip_runtime.h>
#include <stdint.h>

typedef unsigned short ushort_t;
typedef __attribute__((ext_vector_type(8))) short short8;
typedef __attribute__((ext_vector_type(4))) float floatx4;

#define B_    32
#define C_    256
#define O_    256
#define HID_  65
#define HW_   4096
#define KDIM  2304          // C_ * 9
#define XP_H  66            // padded spatial edge
#define XPAD_ELEMS ((size_t)B_ * XP_H * XP_H * C_)   // 35,684,352 bf16
#define WAGG_ELEMS ((size_t)B_ * O_ * KDIM)          // 18,874,368 bf16

static __device__ __forceinline__ unsigned short f2bf(float f) {
  unsigned u = __float_as_uint(f);
  u += 0x7fffu + ((u >> 16) & 1u);        // RNE
  return (unsigned short)(u >> 16);
}

static __device__ __forceinline__ void gld_lds16(const void* g, void* l) {
  // async global->LDS, 16B/lane; LDS dest = wave-uniform base + lane*16
  __builtin_amdgcn_global_load_lds((__attribute__((address_space(1))) void*)(g),
                                   (__attribute__((address_space(3))) void*)(l),
                                   16, 0, 0);
}

// ---------------------------------------------------------------- pool ------
// pooled[b*C + c] = mean over 4096 pixels. One wave per (b,c).
__global__ void pool_kernel(const float* __restrict__ x, float* __restrict__ pooled) {
  const int lane = threadIdx.x & 63;
  const int wv   = threadIdx.x >> 6;
  const int bc   = blockIdx.x * 4 + wv;          // 0..8191
  const float4* p = (const float4*)(x + (size_t)bc * HW_);
  float s = 0.f;
#pragma unroll
  for (int r = 0; r < 16; ++r) {
    float4 v = p[r * 64 + lane];
    s += v.x + v.y + v.z + v.w;
  }
#pragma unroll
  for (int off = 32; off; off >>= 1) s += __shfl_down(s, off, 64);
  if (lane == 0) pooled[bc] = s * (1.f / 4096.f);
}

// ---------------------------------------------------------------- attn ------
// one block per b. h = relu(pooled@w1^T); logits = h@w2^T + b2; softmax over K.
__global__ void attn_kernel(const float* __restrict__ pooled,
                            const float* __restrict__ w1,
                            const float* __restrict__ w2,
                            const float* __restrict__ b2,
                            float* __restrict__ attn) {
  __shared__ float sp[C_];
  __shared__ float sh[HID_];
  const int b = blockIdx.x, t = threadIdx.x;
  sp[t] = pooled[b * C_ + t];
  __syncthreads();
  if (t < HID_) {
    float a = 0.f;
    for (int c = 0; c < C_; ++c) a += sp[c] * w1[t * C_ + c];
    sh[t] = fmaxf(a, 0.f);
  }
  __syncthreads();
  float lg[4];
#pragma unroll
  for (int k = 0; k < 4; ++k) {
    float a = b2[k * O_ + t];
    for (int j = 0; j < HID_; ++j) a += sh[j] * w2[(k * O_ + t) * HID_ + j];
    lg[k] = a * 2.0f;                            // / TEMP (0.5)
  }
  float mx = fmaxf(fmaxf(lg[0], lg[1]), fmaxf(lg[2], lg[3]));
  float e0 = expf(lg[0] - mx), e1 = expf(lg[1] - mx);
  float e2 = expf(lg[2] - mx), e3 = expf(lg[3] - mx);
  float inv = 1.f / (e0 + e1 + e2 + e3);
  attn[(b * 4 + 0) * O_ + t] = e0 * inv;
  attn[(b * 4 + 1) * O_ + t] = e1 * inv;
  attn[(b * 4 + 2) * O_ + t] = e2 * inv;
  attn[(b * 4 + 3) * O_ + t] = e3 * inv;
}

// ----------------------------------------------------------------- agg ------
// wagg[b][o][ck] bf16 with ck = tap*256 + c = sum_k attn[b,k,o]*weight[k,o,c,tap]
// one block per o; thread t owns c = t (its 4x9 weight slice stays in regs).
__global__ void agg_kernel(const float* __restrict__ attn,
                           const float* __restrict__ wt,
                           ushort_t* __restrict__ wagg) {
  const int o = blockIdx.x;
  const int t = threadIdx.x;                     // = c
  float wr[4][9];
#pragma unroll
  for (int k = 0; k < 4; ++k) {
    const float* src = wt + (size_t)(k * O_ + o) * KDIM + t * 9;
#pragma unroll
    for (int n = 0; n < 9; ++n) wr[k][n] = src[n];
  }
  for (int b = 0; b < B_; ++b) {
    const float a0 = attn[(b * 4 + 0) * O_ + o];
    const float a1 = attn[(b * 4 + 1) * O_ + o];
    const float a2 = attn[(b * 4 + 2) * O_ + o];
    const float a3 = attn[(b * 4 + 3) * O_ + o];
    ushort_t* dst = wagg + (size_t)(b * O_ + o) * KDIM;
#pragma unroll
    for (int n = 0; n < 9; ++n) {
      float v = a0 * wr[0][n] + a1 * wr[1][n] + a2 * wr[2][n] + a3 * wr[3][n];
      dst[n * C_ + t] = f2bf(v);
    }
  }
}

// ----------------------------------------------------------------- pad ------
// xpad[b][h+1][w+1][c] (bf16, HWC) from x[b][c][h][w] (fp32, CHW).
// LDS 64x64 transpose tile; borders stay zero from the memset.
__global__ void pad_kernel(const float* __restrict__ x, ushort_t* __restrict__ xpad) {
  __shared__ float tile[64][65];
  const int hwT = blockIdx.x, cT = blockIdx.y, b = blockIdx.z;
  const int t = threadIdx.x;
  const int wl = t & 63, grp = t >> 6;           // grp 0..3
  const int hw0 = hwT * 64, c0 = cT * 64;
  const float* src = x + ((size_t)(b * C_ + c0)) * HW_ + hw0;
#pragma unroll
  for (int i = 0; i < 16; ++i) {
    const int ci = grp + i * 4;
    tile[ci][wl] = src[(size_t)ci * HW_ + wl];
  }
  __syncthreads();
  const int cp = (t & 31) * 2, g2 = t >> 5;      // g2 0..7
#pragma unroll
  for (int i = 0; i < 8; ++i) {
    const int hwi = g2 + i * 8;
    const int hw = hw0 + hwi;
    const int h = hw >> 6, w = hw & 63;
    ushort2 v;
    v.x = f2bf(tile[cp][hwi]);
    v.y = f2bf(tile[cp + 1][hwi]);
    *(ushort2*)(xpad + (((size_t)b * XP_H + (h + 1)) * XP_H + (w + 1)) * C_ + c0 + cp) = v;
  }
}

// ---------------------------------------------------------------- gemm ------
// per block: one b, 128-o tile, 128-hw tile. K = 9 taps x 256 c, BK = 32.
// A = wagg[b][o][ck] (k-contig), B = im2col x from HWC xpad (k-contig in c).
// Both staged via global_load_lds w=16 into XOR-swizzled LDS; frag reads are
// ds_read_b128 with 2-way bank aliasing (free).
__global__ __launch_bounds__(256) void gemm_kernel(const ushort_t* __restrict__ xpad,
                                                   const ushort_t* __restrict__ wagg,
                                                   float* __restrict__ out) {
  __shared__ short lA[128 * 32];                 // [o_row][k32], swizzled, 8KB
  __shared__ short lB[128 * 32];                 // [hw_row][k32], swizzled, 8KB

  const int hwT = blockIdx.x;                    // 0..31
  const int oT  = blockIdx.y;                    // 0..1
  const int b   = blockIdx.z;                    // 0..31
  const int t    = threadIdx.x;
  const int lane = t & 63;
  const int wv   = t >> 6;

  const int hwBase = hwT << 7;
  const int h0     = hwT << 1;                   // 2 image rows per hw-tile
  const int oBase  = oT << 7;

  // staging geometry: chunk = 16 rows x 32 k = 1KB; wave wv owns chunks 2wv,2wv+1
  const int rowIC = lane >> 2;                   // 0..15
  const int slot  = lane & 3;                    // physical 16B slot in row
  const int cch   = slot ^ ((lane >> 3) & 3);    // logical k-chunk (swizzle)

  size_t aG[2], bG[2];
  int ldsOff[2];
#pragma unroll
  for (int q = 0; q < 2; ++q) {
    const int chunk = wv * 2 + q;                // 0..7
    const int r = chunk * 16 + rowIC;            // row in 128-tile
    aG[q] = (size_t)(b * O_ + oBase + r) * KDIM + cch * 8;
    const int hl = r >> 6, wl2 = r & 63;
    bG[q] = ((size_t)(b * XP_H + h0 + hl) * XP_H + wl2) * C_ + cch * 8;
    ldsOff[q] = chunk * 512;                     // shorts
  }

  // fragment geometry (mfma_f32_16x16x32_bf16): A[m=lane&15][k=quad*8+j]
  const int lm   = lane & 15;
  const int quad = lane >> 4;
  const int mW = (wv & 1) << 6;
  const int nW = (wv >> 1) << 6;
  const int slotF = quad ^ ((lm >> 1) & 3);      // de-swizzle
  int aOff[4], bOff[4];
#pragma unroll
  for (int i = 0; i < 4; ++i) {
    aOff[i] = (mW + i * 16 + lm) * 32 + slotF * 8;   // shorts (16B aligned)
    bOff[i] = (nW + i * 16 + lm) * 32 + slotF * 8;
  }

  floatx4 acc[4][4] = {};

  for (int tap = 0; tap < 9; ++tap) {
    const int toff = (tap / 3) * XP_H + (tap % 3);   // i*66 + j
#pragma unroll 1
    for (int c0 = 0; c0 < C_; c0 += 32) {
      const int kk = tap * C_ + c0;
      __syncthreads();
#pragma unroll
      for (int q = 0; q < 2; ++q) {
        gld_lds16(wagg + aG[q] + kk, lA + ldsOff[q]);
        gld_lds16(xpad + bG[q] + (size_t)toff * C_ + c0, lB + ldsOff[q]);
      }
      __builtin_amdgcn_s_waitcnt(0x0f70);        // vmcnt(0)
      __syncthreads();

      short8 af[4], bf[4];
#pragma unroll
      for (int i = 0; i < 4; ++i) af[i] = *(const short8*)(lA + aOff[i]);
#pragma unroll
      for (int i = 0; i < 4; ++i) bf[i] = *(const short8*)(lB + bOff[i]);
#pragma unroll
      for (int mi = 0; mi < 4; ++mi)
#pragma unroll
        for (int ni = 0; ni < 4; ++ni)
          acc[mi][ni] = __builtin_amdgcn_mfma_f32_16x16x32_bf16(
              af[mi], bf[ni], acc[mi][ni], 0, 0, 0);
    }
  }

  // epilogue: D row = (quad*4 + reg), col = lane&15  [verified m89/m91]
  const size_t outBase = (size_t)b * O_ * HW_;
#pragma unroll
  for (int mi = 0; mi < 4; ++mi) {
#pragma unroll
    for (int ni = 0; ni < 4; ++ni) {
      const int hw = hwBase + nW + ni * 16 + lm;
#pragma unroll
      for (int r = 0; r < 4; ++r) {
        const int o = oBase + mW + mi * 16 + quad * 4 + r;
        out[outBase + (size_t)o * HW_ + hw] = acc[mi][ni][r];
      }
    }
  }
}

// -------------------------------------------------------------- launch ------
extern "C" void kernel_launch(void* const* d_in, const int* in_sizes, int n_in,
                              void* d_out, int out_size, void* d_ws, size_t ws_size,
                              hipStream_t stream) {
  const float* x  = (const float*)d_in[0];   // [32,256,64,64]
  const float* w1 = (const float*)d_in[1];   // [65,256]
  const float* w2 = (const float*)d_in[2];   // [1024,65]
  const float* b2 = (const float*)d_in[3];   // [1024]
  const float* wt = (const float*)d_in[4];   // [4,256,256,3,3]
  float* out = (float*)d_out;                // [32,256,64,64]

  char* ws = (char*)d_ws;
  ushort_t* xpad = (ushort_t*)ws;                                  // 71.4 MB
  ushort_t* wagg = (ushort_t*)(ws + XPAD_ELEMS * 2);               // 37.7 MB
  float* pooled  = (float*)(ws + XPAD_ELEMS * 2 + WAGG_ELEMS * 2); // 32 KB
  float* attn    = pooled + B_ * C_;                               // 128 KB

  hipMemsetAsync(xpad, 0, XPAD_ELEMS * 2, stream);                 // pad borders
  pool_kernel<<<2048, 256, 0, stream>>>(x, pooled);
  attn_kernel<<<B_, 256, 0, stream>>>(pooled, w1, w2, b2, attn);
  agg_kernel<<<O_, 256, 0, stream>>>(attn, wt, wagg);
  pad_kernel<<<dim3(64, 4, B_), 256, 0, stream>>>(x, xpad);
  gemm_kernel<<<dim3(32, 2, B_), 256, 0, stream>>>(xpad, wagg, out);
}

// Round 2
// 446.832 us; speedup vs baseline: 1.1169x; 1.1169x over previous
//
#include <hip/hip_runtime.h>
#include <stdint.h>

typedef unsigned short ushort_t;
typedef __attribute__((ext_vector_type(8))) short short8;
typedef __attribute__((ext_vector_type(4))) float floatx4;

#define B_    32
#define C_    256
#define O_    256
#define HID_  65
#define HW_   4096
#define KDIM  2304          // C_ * 9
#define XP_H  66            // padded spatial edge
#define XPAD_ELEMS ((size_t)B_ * XP_H * XP_H * C_)   // 35,684,352 bf16
#define WAGG_ELEMS ((size_t)B_ * O_ * KDIM)          // 18,874,368 bf16

static __device__ __forceinline__ unsigned short f2bf(float f) {
  unsigned u = __float_as_uint(f);
  u += 0x7fffu + ((u >> 16) & 1u);        // RNE
  return (unsigned short)(u >> 16);
}

static __device__ __forceinline__ void gld_lds16(const void* g, void* l) {
  // async global->LDS, 16B/lane; LDS dest = wave-uniform base + lane*16
  __builtin_amdgcn_global_load_lds((__attribute__((address_space(1))) void*)(g),
                                   (__attribute__((address_space(3))) void*)(l),
                                   16, 0, 0);
}

// -------------------------------------------------------------- border ------
// zero only the pad borders of xpad (4.3 MB) instead of memsetting 71 MB.
// interior is fully overwritten by pad_kernel.
__global__ void border_kernel(ushort_t* __restrict__ xpad) {
  const int b = blockIdx.x, t = threadIdx.x;
  uint4 z = {0u, 0u, 0u, 0u};
  uint4* base = (uint4*)(xpad + (size_t)b * XP_H * XP_H * C_);
  // row stride = 66*256 shorts = 2112 uint4; w stride = 256 shorts = 32 uint4
  for (int i = t; i < 2112; i += 256) {            // rows h=0 and h=65
    base[i] = z;
    base[(size_t)65 * 2112 + i] = z;
  }
  for (int i = t; i < 64 * 32; i += 256) {         // cols w=0 and w=65, h=1..64
    const int h = 1 + (i >> 5), s = i & 31;
    base[(size_t)h * 2112 + s] = z;
    base[(size_t)h * 2112 + 65 * 32 + s] = z;
  }
}

// ----------------------------------------------------------------- pad ------
// xpad[b][h+1][w+1][c] (bf16, HWC) from x[b][c][h][w] (fp32, CHW), PLUS
// per-block pooling partials: partial[hwT][b*C+c] = sum over this tile's 64 hw.
__global__ void pad_kernel(const float* __restrict__ x, ushort_t* __restrict__ xpad,
                           float* __restrict__ partial) {
  __shared__ float tile[64][65];
  const int hwT = blockIdx.x, cT = blockIdx.y, b = blockIdx.z;
  const int t = threadIdx.x;
  const int wl = t & 63, grp = t >> 6;             // grp 0..3
  const int hw0 = hwT * 64, c0 = cT * 64;
  const float* src = x + ((size_t)(b * C_ + c0)) * HW_ + hw0;
#pragma unroll
  for (int i = 0; i < 16; ++i) {
    const int ci = grp + i * 4;
    tile[ci][wl] = src[(size_t)ci * HW_ + wl];
  }
  __syncthreads();
  // pooling partial: threads 0..63 each own one c; banks (t+i)%32 -> 2-way, free
  if (t < 64) {
    float s = 0.f;
#pragma unroll
    for (int i = 0; i < 64; ++i) s += tile[t][i];
    partial[(size_t)hwT * (B_ * C_) + b * C_ + c0 + t] = s;
  }
  // transpose + bf16 convert + store
  const int cp = (t & 31) * 2, g2 = t >> 5;        // g2 0..7
#pragma unroll
  for (int i = 0; i < 8; ++i) {
    const int hwi = g2 + i * 8;
    const int hw = hw0 + hwi;
    const int h = hw >> 6, w = hw & 63;
    ushort2 v;
    v.x = f2bf(tile[cp][hwi]);
    v.y = f2bf(tile[cp + 1][hwi]);
    *(ushort2*)(xpad + (((size_t)b * XP_H + (h + 1)) * XP_H + (w + 1)) * C_ + c0 + cp) = v;
  }
}

// ---------------------------------------------------------------- attn ------
// one block per b. reduce partials -> pooled; h = relu(pooled@w1^T);
// logits = h@w2^T + b2; softmax over K.
__global__ void attn_kernel(const float* __restrict__ partial,
                            const float* __restrict__ w1,
                            const float* __restrict__ w2,
                            const float* __restrict__ b2,
                            float* __restrict__ attn) {
  __shared__ float sp[C_];
  __shared__ float sh[HID_];
  const int b = blockIdx.x, t = threadIdx.x;
  {
    float s = 0.f;
#pragma unroll
    for (int i = 0; i < 64; ++i) s += partial[(size_t)i * (B_ * C_) + b * C_ + t];
    sp[t] = s * (1.f / 4096.f);
  }
  __syncthreads();
  if (t < HID_) {
    float a = 0.f;
    for (int c = 0; c < C_; ++c) a += sp[c] * w1[t * C_ + c];
    sh[t] = fmaxf(a, 0.f);
  }
  __syncthreads();
  float lg[4];
#pragma unroll
  for (int k = 0; k < 4; ++k) {
    float a = b2[k * O_ + t];
    for (int j = 0; j < HID_; ++j) a += sh[j] * w2[(k * O_ + t) * HID_ + j];
    lg[k] = a * 2.0f;                              // / TEMP (0.5)
  }
  float mx = fmaxf(fmaxf(lg[0], lg[1]), fmaxf(lg[2], lg[3]));
  float e0 = expf(lg[0] - mx), e1 = expf(lg[1] - mx);
  float e2 = expf(lg[2] - mx), e3 = expf(lg[3] - mx);
  float inv = 1.f / (e0 + e1 + e2 + e3);
  attn[(b * 4 + 0) * O_ + t] = e0 * inv;
  attn[(b * 4 + 1) * O_ + t] = e1 * inv;
  attn[(b * 4 + 2) * O_ + t] = e2 * inv;
  attn[(b * 4 + 3) * O_ + t] = e3 * inv;
}

// ----------------------------------------------------------------- agg ------
// wagg[b][o][ck] bf16 with ck = tap*256 + c = sum_k attn[b,k,o]*weight[k,o,c,tap]
__global__ void agg_kernel(const float* __restrict__ attn,
                           const float* __restrict__ wt,
                           ushort_t* __restrict__ wagg) {
  const int o = blockIdx.x;
  const int t = threadIdx.x;                       // = c
  float wr[4][9];
#pragma unroll
  for (int k = 0; k < 4; ++k) {
    const float* src = wt + (size_t)(k * O_ + o) * KDIM + t * 9;
#pragma unroll
    for (int n = 0; n < 9; ++n) wr[k][n] = src[n];
  }
  for (int b = 0; b < B_; ++b) {
    const float a0 = attn[(b * 4 + 0) * O_ + o];
    const float a1 = attn[(b * 4 + 1) * O_ + o];
    const float a2 = attn[(b * 4 + 2) * O_ + o];
    const float a3 = attn[(b * 4 + 3) * O_ + o];
    ushort_t* dst = wagg + (size_t)(b * O_ + o) * KDIM;
#pragma unroll
    for (int n = 0; n < 9; ++n) {
      float v = a0 * wr[0][n] + a1 * wr[1][n] + a2 * wr[2][n] + a3 * wr[3][n];
      dst[n * C_ + t] = f2bf(v);
    }
  }
}

// ---------------------------------------------------------------- gemm ------
// per block: one b, 128-o tile, 128-hw tile. K = 9 taps x 256 c, BK = 64
// (36 K-steps x 32 MFMA vs round-1's 72 x 16 — halves barrier-drain count).
// Rows are 64 shorts = 8 slots of 16B; physical slot = logical ^ (row & 7)
// keeps global_load_lds w=16 contiguity and <=2-way LDS bank aliasing.
__global__ __launch_bounds__(256) void gemm_kernel(const ushort_t* __restrict__ xpad,
                                                   const ushort_t* __restrict__ wagg,
                                                   float* __restrict__ out) {
  __shared__ short lA[128 * 64];                   // 16 KB
  __shared__ short lB[128 * 64];                   // 16 KB

  const int hwT = blockIdx.x;                      // 0..31
  const int oT  = blockIdx.y;                      // 0..1
  const int b   = blockIdx.z;                      // 0..31
  const int t    = threadIdx.x;
  const int lane = t & 63;
  const int wv   = t >> 6;

  const int hwBase = hwT << 7;
  const int h0     = hwT << 1;                     // 2 image rows per hw-tile
  const int oBase  = oT << 7;

  // staging: per pass a wave covers 8 rows x 8 slots (1 KB). wave wv owns
  // rows wv*32 + q*8 + (lane>>3), q = 0..3. physical slot = lane&7.
  const int rS = lane >> 3;                        // 0..7
  const int pS = lane & 7;                         // physical 16B slot
  size_t aG[4], bG[4];
  int ldsOff[4];
#pragma unroll
  for (int q = 0; q < 4; ++q) {
    const int row = wv * 32 + q * 8 + rS;
    const int lch = pS ^ (row & 7);                // logical k-chunk (swizzle)
    aG[q] = (size_t)(b * O_ + oBase + row) * KDIM + lch * 8;
    const int hl = row >> 6, wl2 = row & 63;
    bG[q] = ((size_t)(b * XP_H + h0 + hl) * XP_H + wl2) * C_ + lch * 8;
    ldsOff[q] = (wv * 32 + q * 8) * 64;            // shorts
  }

  // fragment geometry (mfma_f32_16x16x32_bf16): A[m=lane&15][k=quad*8+j]
  const int lm   = lane & 15;
  const int quad = lane >> 4;
  const int mW = (wv & 1) << 6;
  const int nW = (wv >> 1) << 6;
  int aOff[2][4], bOff[2][4];
#pragma unroll
  for (int h = 0; h < 2; ++h)
#pragma unroll
    for (int i = 0; i < 4; ++i) {
      const int ps = ((h * 4 + quad) ^ (lm & 7)) * 8;   // de-swizzle, shorts
      aOff[h][i] = (mW + i * 16 + lm) * 64 + ps;
      bOff[h][i] = (nW + i * 16 + lm) * 64 + ps;
    }

  floatx4 acc[4][4] = {};

  for (int tap = 0; tap < 9; ++tap) {
    const int toff = (tap / 3) * XP_H + (tap % 3);      // i*66 + j
#pragma unroll 1
    for (int c0 = 0; c0 < C_; c0 += 64) {
      const int kk = tap * C_ + c0;
      __syncthreads();
#pragma unroll
      for (int q = 0; q < 4; ++q) {
        gld_lds16(wagg + aG[q] + kk, lA + ldsOff[q]);
        gld_lds16(xpad + bG[q] + (size_t)toff * C_ + c0, lB + ldsOff[q]);
      }
      __builtin_amdgcn_s_waitcnt(0x0f70);               // vmcnt(0)
      __syncthreads();

#pragma unroll
      for (int h = 0; h < 2; ++h) {
        short8 af[4], bf[4];
#pragma unroll
        for (int i = 0; i < 4; ++i) af[i] = *(const short8*)(lA + aOff[h][i]);
#pragma unroll
        for (int i = 0; i < 4; ++i) bf[i] = *(const short8*)(lB + bOff[h][i]);
#pragma unroll
        for (int mi = 0; mi < 4; ++mi)
#pragma unroll
          for (int ni = 0; ni < 4; ++ni)
            acc[mi][ni] = __builtin_amdgcn_mfma_f32_16x16x32_bf16(
                af[mi], bf[ni], acc[mi][ni], 0, 0, 0);
      }
    }
  }

  // epilogue: D row = (quad*4 + reg), col = lane&15  [verified m89/m91]
  const size_t outBase = (size_t)b * O_ * HW_;
#pragma unroll
  for (int mi = 0; mi < 4; ++mi) {
#pragma unroll
    for (int ni = 0; ni < 4; ++ni) {
      const int hw = hwBase + nW + ni * 16 + lm;
#pragma unroll
      for (int r = 0; r < 4; ++r) {
        const int o = oBase + mW + mi * 16 + quad * 4 + r;
        out[outBase + (size_t)o * HW_ + hw] = acc[mi][ni][r];
      }
    }
  }
}

// -------------------------------------------------------------- launch ------
extern "C" void kernel_launch(void* const* d_in, const int* in_sizes, int n_in,
                              void* d_out, int out_size, void* d_ws, size_t ws_size,
                              hipStream_t stream) {
  const float* x  = (const float*)d_in[0];   // [32,256,64,64]
  const float* w1 = (const float*)d_in[1];   // [65,256]
  const float* w2 = (const float*)d_in[2];   // [1024,65]
  const float* b2 = (const float*)d_in[3];   // [1024]
  const float* wt = (const float*)d_in[4];   // [4,256,256,3,3]
  float* out = (float*)d_out;                // [32,256,64,64]

  char* ws = (char*)d_ws;
  ushort_t* xpad = (ushort_t*)ws;                                  // 71.4 MB
  ushort_t* wagg = (ushort_t*)(ws + XPAD_ELEMS * 2);               // 37.7 MB
  float* partial = (float*)(ws + XPAD_ELEMS * 2 + WAGG_ELEMS * 2); // 2 MB
  float* attn    = partial + 64 * B_ * C_;                         // 128 KB

  border_kernel<<<B_, 256, 0, stream>>>(xpad);
  pad_kernel<<<dim3(64, 4, B_), 256, 0, stream>>>(x, xpad, partial);
  attn_kernel<<<B_, 256, 0, stream>>>(partial, w1, w2, b2, attn);
  agg_kernel<<<O_, 256, 0, stream>>>(attn, wt, wagg);
  gemm_kernel<<<dim3(32, 2, B_), 256, 0, stream>>>(xpad, wagg, out);
}